// Round 6
// baseline (683.894 us; speedup 1.0000x reference)
//
#include <hip/hip_runtime.h>
#include <stdint.h>

#define S 64
#define NSQ 32
#define Lc 2048
#define Cc 512
#define Ec 128
#define OUT_H (S*NSQ*Lc)   /* 4194304 */

typedef __bf16 bf16x8 __attribute__((ext_vector_type(8)));
typedef float floatx4 __attribute__((ext_vector_type(4)));

__device__ __forceinline__ unsigned short f2bf(float f){
  union { float f; uint32_t u; } v; v.f = f;
  uint32_t r = v.u + 0x7fffu + ((v.u >> 16) & 1u);
  return (unsigned short)(r >> 16);
}

// ---------------------------------------------------------------------------
// k_prep: dynamic weights w[s][c][k], b[s][c]; W1->bf16; W2 rearrange->bf16;
// zero logdet.   grid 512 x 256
// ---------------------------------------------------------------------------
__global__ void k_prep(const float* __restrict__ emb,
                       const float* __restrict__ Wa, const float* __restrict__ ba,
                       const float* __restrict__ Wb, const float* __restrict__ bb,
                       const float* __restrict__ W1, const float* __restrict__ W2,
                       float* __restrict__ dynW, float* __restrict__ dynB,
                       unsigned short* __restrict__ W1bf, unsigned short* __restrict__ W2bf,
                       float* __restrict__ out)
{
  __shared__ float embl[Ec];
  int tid = threadIdx.x;
  int b = blockIdx.x;          // 512 blocks, 8 per sample
  int s = b >> 3;
  int o = ((b & 7) << 8) | tid;   // 0..2047 (1536 dynW dots + 512 dynB dots)
  if (tid < Ec) embl[tid] = emb[s*Ec + tid];
  __syncthreads();
  const float* row; float bias; float* dst;
  if (o < 1536) { row = Wa + o*Ec; bias = ba[o]; dst = dynW + s*1536 + o; }
  else { int c = o - 1536; row = Wb + c*Ec; bias = bb[c]; dst = dynB + s*Cc + c; }
  float acc = bias;
  const float4* r4 = (const float4*)row;
  #pragma unroll 8
  for (int e = 0; e < Ec/4; e++) {
    float4 rv = r4[e];
    acc += embl[4*e]*rv.x + embl[4*e+1]*rv.y + embl[4*e+2]*rv.z + embl[4*e+3]*rv.w;
  }
  *dst = acc;

  int gtid = b*256 + tid;      // 0..131071
  {
    float2 wv = ((const float2*)W1)[gtid];
    W1bf[2*gtid]   = f2bf(wv.x);
    W1bf[2*gtid+1] = f2bf(wv.y);
  }
  // W2 rearrange: dst [k][j][c] <- src [j][c][k]  (49152 elems)
  if (gtid < 3*32*Cc) {
    int k = gtid >> 14;
    int rem = gtid & 16383;
    int j = rem >> 9, c = rem & 511;
    W2bf[gtid] = f2bf(W2[j*1536 + c*3 + k]);
  }
  if (gtid < S) out[OUT_H + gtid] = 0.f;   // logdet accumulators
}

// ---------------------------------------------------------------------------
// k_fused3: 8-wave block per (l-tile, sample); 2 blocks/CU (LDS 77.9 KB).
//   phase A: acc[512 o][64 ll] = W1 @ x; BK=64 (2 h-rows/chunk), 8 chunks,
//            ONE barrier per chunk: Bs double-buffered, A-frags (W1, L2)
//            prefetched a chunk ahead so the barrier vmcnt-drain is covered.
//   x2t:     [66][520] bf16 = relu(acc+b1); rows 64/65 zero (conv pad).
//   phase B: conv KW=3 via MFMA; W2-frags direct from L2; x2 from LDS.
//   phase C: h1 copy + sigmoid/affine/out + logdet reduce.
// lb = t*62 - 1; valid outputs lo in [0,62).
// ---------------------------------------------------------------------------
__global__ void __launch_bounds__(512, 4) k_fused3(
    const float* __restrict__ h,
    const unsigned short* __restrict__ W1bf, const float* __restrict__ b1,
    const unsigned short* __restrict__ W2bf, const float* __restrict__ b2,
    const float* __restrict__ dynW, const float* __restrict__ dynB,
    float* __restrict__ out)
{
  extern __shared__ char smem[];
  unsigned short* BsA[2];
  BsA[0] = (unsigned short*)smem;                         // [64][72]
  BsA[1] = (unsigned short*)(smem + 9216);                // [64][72]
  unsigned short* x2t = (unsigned short*)smem;            // [66][520] (aliases)
  float* x3b = (float*)(smem + 68640);                    // [64][36]
  float* red = (float*)(smem + 77856);                    // [8]

  int tid = threadIdx.x;
  int t = blockIdx.x, s = blockIdx.y;
  int lb = t*62 - 1;
  int w = tid >> 6, ln16 = tid & 15, quad = (tid & 63) >> 4;
  int cl = tid & 63;                   // staging: channel lane (64 c/chunk)
  int ll0 = w*8;                       // staging: 8 ll per thread-group

  const float* hbase = h + s*(NSQ*Lc);
  const float* dwp = dynW + s*1536;
  const float* dbp = dynB + s*Cc;

  floatx4 acc[4][4];
  #pragma unroll
  for (int mi = 0; mi < 4; mi++)
    #pragma unroll
    for (int ni = 0; ni < 4; ni++)
      acc[mi][ni] = (floatx4){0.f,0.f,0.f,0.f};

  // compute x(c0+cl, ll0..ll0+7) and write to buffer BUF_
  #define STAGE(ch_, BUF_) {                                                  \
    int c_ = (ch_)*64 + cl;                                                   \
    const float* hr_ = hbase + (c_ >> 5)*Lc;                                  \
    float w0c = dwp[c_*3], w1c = dwp[c_*3+1], w2c = dwp[c_*3+2];              \
    float bxc = dbp[c_];                                                      \
    float ph[10];                                                             \
    int base_ = lb + ll0 - 1;                                                 \
    _Pragma("unroll")                                                         \
    for (int m = 0; m < 10; m++) {                                            \
      int hi_ = base_ + m;                                                    \
      ph[m] = ((unsigned)hi_ < 2048u) ? hr_[hi_] : 0.f;                       \
    }                                                                         \
    _Pragma("unroll")                                                         \
    for (int i = 0; i < 8; i++) {                                             \
      float v_ = fmaxf(w0c*ph[i] + w1c*ph[i+1] + w2c*ph[i+2] + bxc, 0.f);     \
      (BUF_)[(ll0 + i)*72 + cl] = f2bf(v_);                                   \
    }                                                                         \
  }

  #define LOADAF(ch_, kh_, AF_) {                                             \
    _Pragma("unroll")                                                         \
    for (int mi = 0; mi < 4; mi++)                                            \
      (AF_)[mi] = *(const bf16x8*)&W1bf[(w*64 + mi*16 + ln16)*512             \
                                        + (ch_)*64 + (kh_)*32 + quad*8];      \
  }

  // -------- phase A: 8 K-chunks of 64 channels, 1 barrier each --------
  bf16x8 af_c[4], af_n[4], af1[4];
  LOADAF(0, 0, af_c);
  STAGE(0, BsA[0]);
  __syncthreads();
  for (int ch = 0; ch < 8; ch++) {
    int buf = ch & 1;
    LOADAF(ch, 1, af1);                  // kh1 frags, consumed after kh0 MFMAs
    if (ch < 7) {
      LOADAF(ch + 1, 0, af_n);           // next chunk kh0, consumed next iter
      STAGE(ch + 1, BsA[buf ^ 1]);       // overlaps this chunk's MFMAs
    }
    // kh0 MFMAs
    #pragma unroll
    for (int ni = 0; ni < 4; ni++) {
      bf16x8 bf = *(const bf16x8*)&BsA[buf][(ni*16 + ln16)*72 + quad*8];
      #pragma unroll
      for (int mi = 0; mi < 4; mi++)
        acc[mi][ni] = __builtin_amdgcn_mfma_f32_16x16x32_bf16(af_c[mi], bf, acc[mi][ni], 0, 0, 0);
    }
    // kh1 MFMAs
    #pragma unroll
    for (int ni = 0; ni < 4; ni++) {
      bf16x8 bf = *(const bf16x8*)&BsA[buf][(ni*16 + ln16)*72 + 32 + quad*8];
      #pragma unroll
      for (int mi = 0; mi < 4; mi++)
        acc[mi][ni] = __builtin_amdgcn_mfma_f32_16x16x32_bf16(af1[mi], bf, acc[mi][ni], 0, 0, 0);
    }
    #pragma unroll
    for (int mi = 0; mi < 4; mi++) af_c[mi] = af_n[mi];
    __syncthreads();                     // publishes Bs[buf^1] for next iter
  }

  // -------- epilogue A: relu+b1 -> x2t (bf16), zero-pad invalid l --------
  #pragma unroll
  for (int mi = 0; mi < 4; mi++) {
    int o = w*64 + mi*16 + quad*4;
    float4 b1v = *(const float4*)(b1 + o);
    #pragma unroll
    for (int ni = 0; ni < 4; ni++) {
      int ll = ni*16 + ln16;
      int gl = lb + ll;
      ushort4 st;
      if ((unsigned)gl < 2048u) {
        st.x = f2bf(fmaxf(acc[mi][ni][0] + b1v.x, 0.f));
        st.y = f2bf(fmaxf(acc[mi][ni][1] + b1v.y, 0.f));
        st.z = f2bf(fmaxf(acc[mi][ni][2] + b1v.z, 0.f));
        st.w = f2bf(fmaxf(acc[mi][ni][3] + b1v.w, 0.f));
      } else {
        st.x = 0; st.y = 0; st.z = 0; st.w = 0;   // conv2 zero-pad columns
      }
      *(ushort4*)&x2t[ll*520 + o] = st;
    }
  }
  for (int i = tid; i < 520; i += 512)
    ((uint32_t*)&x2t[64*520])[i] = 0u;             // rows 64,65 = 0
  __syncthreads();

  // -------- phase B: KW=3 conv via MFMA; wave = (jh, nh 0..3) --------
  {
    int jh = w & 1, nh = w >> 1;
    floatx4 ca = (floatx4){0.f,0.f,0.f,0.f};
    #pragma unroll
    for (int k = 0; k < 3; k++) {
      const unsigned short* Wk = W2bf + k*16384 + (jh*16 + ln16)*512;
      const unsigned short* xr = x2t + (nh*16 + ln16 + k)*520;
      #pragma unroll
      for (int c0 = 0; c0 < 512; c0 += 32) {
        bf16x8 a0 = *(const bf16x8*)&Wk[c0 + quad*8];
        bf16x8 v0 = *(const bf16x8*)&xr[c0 + quad*8];
        ca = __builtin_amdgcn_mfma_f32_16x16x32_bf16(a0, v0, ca, 0, 0, 0);
      }
    }
    float4 b2v = *(const float4*)(b2 + jh*16 + quad*4);
    int lo = nh*16 + ln16;
    float4 st;
    st.x = ca[0] + b2v.x;
    st.y = ca[1] + b2v.y;
    st.z = ca[2] + b2v.z;
    st.w = ca[3] + b2v.w;
    *(float4*)&x3b[lo*36 + jh*16 + quad*4] = st;
  }
  __syncthreads();

  // -------- phase C: h1 copy + sigmoid/affine/out + logdet --------
  float ld = 0.f;
  #pragma unroll
  for (int i = 0; i < 4; i++) {
    int idx = tid + i*512;           // 0..2047 = (q 0..31) x (lo 0..63)
    int lo = idx & 63, q = idx >> 6;
    int l = t*62 + lo;
    if (lo < 62 && l < 2048) {
      int gi = s*(NSQ*Lc) + q*Lc + l;
      if (q < 16) {
        out[gi] = h[gi];             // h1 passthrough
      } else {
        float sv = 1.f / (1.f + __expf(-(x3b[lo*36 + (q-16)] + 2.f))) + 1e-7f;
        float mv = x3b[lo*36 + (q-16) + 16];
        out[gi] = sv * (h[gi] + mv);
        ld += __logf(sv);
      }
    }
  }
  #pragma unroll
  for (int off = 32; off > 0; off >>= 1) ld += __shfl_down(ld, off);
  if ((tid & 63) == 0) red[w] = ld;
  __syncthreads();
  if (tid == 0) {
    float tot = 0.f;
    #pragma unroll
    for (int i = 0; i < 8; i++) tot += red[i];
    atomicAdd(&out[OUT_H + s], tot);
  }
}

// ---------------------------------------------------------------------------
extern "C" void kernel_launch(void* const* d_in, const int* in_sizes, int n_in,
                              void* d_out, int out_size, void* d_ws, size_t ws_size,
                              hipStream_t stream) {
  const float* h   = (const float*)d_in[0];
  const float* emb = (const float*)d_in[1];
  const float* Wa  = (const float*)d_in[2];
  const float* ba  = (const float*)d_in[3];
  const float* Wb  = (const float*)d_in[4];
  const float* bb  = (const float*)d_in[5];
  const float* W1  = (const float*)d_in[6];
  const float* b1  = (const float*)d_in[7];
  const float* W2  = (const float*)d_in[8];
  const float* b2  = (const float*)d_in[9];
  float* out = (float*)d_out;
  char* ws = (char*)d_ws;

  float* dynW = (float*)(ws + 0);                          // 384 KiB
  float* dynB = (float*)(ws + 393216);                     // 128 KiB
  unsigned short* W1bf = (unsigned short*)(ws + 524288);   // 512 KiB
  unsigned short* W2bf = (unsigned short*)(ws + 1048576);  // 96 KiB
  if (ws_size < 1179648ull) return;                        // ~1.2 MB needed

  const int smem_bytes = 77888;  // max(phaseA 18432, x2t 68640 + x3b 9216 + red 32)
  (void)hipFuncSetAttribute((const void*)k_fused3,
                            hipFuncAttributeMaxDynamicSharedMemorySize,
                            smem_bytes);

  k_prep<<<512, 256, 0, stream>>>(emb, Wa, ba, Wb, bb, W1, W2,
                                  dynW, dynB, W1bf, W2bf, out);
  k_fused3<<<dim3(34, 64), 512, smem_bytes, stream>>>(h, W1bf, b1, W2bf, b2,
                                                      dynW, dynB, out);
}

// Round 7
// 417.701 us; speedup vs baseline: 1.6373x; 1.6373x over previous
//
#include <hip/hip_runtime.h>
#include <stdint.h>

#define S 64
#define NSQ 32
#define Lc 2048
#define Cc 512
#define Ec 128
#define OUT_H (S*NSQ*Lc)   /* 4194304 */

typedef __bf16 bf16x8 __attribute__((ext_vector_type(8)));
typedef float floatx4 __attribute__((ext_vector_type(4)));

__device__ __forceinline__ unsigned short f2bf(float f){
  union { float f; uint32_t u; } v; v.f = f;
  uint32_t r = v.u + 0x7fffu + ((v.u >> 16) & 1u);
  return (unsigned short)(r >> 16);
}

// ---------------------------------------------------------------------------
// k_prep: dynamic weights w[s][c][k], b[s][c]; W1->bf16; W2 rearrange->bf16;
// zero logdet.   grid 512 x 256
// ---------------------------------------------------------------------------
__global__ void k_prep(const float* __restrict__ emb,
                       const float* __restrict__ Wa, const float* __restrict__ ba,
                       const float* __restrict__ Wb, const float* __restrict__ bb,
                       const float* __restrict__ W1, const float* __restrict__ W2,
                       float* __restrict__ dynW, float* __restrict__ dynB,
                       unsigned short* __restrict__ W1bf, unsigned short* __restrict__ W2bf,
                       float* __restrict__ out)
{
  __shared__ float embl[Ec];
  int tid = threadIdx.x;
  int b = blockIdx.x;          // 512 blocks, 8 per sample
  int s = b >> 3;
  int o = ((b & 7) << 8) | tid;   // 0..2047 (1536 dynW dots + 512 dynB dots)
  if (tid < Ec) embl[tid] = emb[s*Ec + tid];
  __syncthreads();
  const float* row; float bias; float* dst;
  if (o < 1536) { row = Wa + o*Ec; bias = ba[o]; dst = dynW + s*1536 + o; }
  else { int c = o - 1536; row = Wb + c*Ec; bias = bb[c]; dst = dynB + s*Cc + c; }
  float acc = bias;
  const float4* r4 = (const float4*)row;
  #pragma unroll 8
  for (int e = 0; e < Ec/4; e++) {
    float4 rv = r4[e];
    acc += embl[4*e]*rv.x + embl[4*e+1]*rv.y + embl[4*e+2]*rv.z + embl[4*e+3]*rv.w;
  }
  *dst = acc;

  int gtid = b*256 + tid;      // 0..131071
  {
    float2 wv = ((const float2*)W1)[gtid];
    W1bf[2*gtid]   = f2bf(wv.x);
    W1bf[2*gtid+1] = f2bf(wv.y);
  }
  // W2 rearrange: dst [k][j][c] <- src [j][c][k]  (49152 elems)
  if (gtid < 3*32*Cc) {
    int k = gtid >> 14;
    int rem = gtid & 16383;
    int j = rem >> 9, c = rem & 511;
    W2bf[gtid] = f2bf(W2[j*1536 + c*3 + k]);
  }
  if (gtid < S) out[OUT_H + gtid] = 0.f;   // logdet accumulators
}

// ---------------------------------------------------------------------------
// k_fused4: 8-wave (512-thr) block per (l-tile, sample); 1 block/CU (LDS).
//   phase A (NO LDS, NO barriers): acc[512 o][128 ll] = W1 @ x.
//     Wave tile 128o x 64l: waves = (ot 0..3) x (lh 0..1); 16 K-chunks of 32c.
//     B-fragments computed per-lane in registers (depthwise 3-tap + relu +
//     bf16); A-fragments (W1) straight from L2. acc[8][4] lives in AGPRs.
//   epilogue A: relu(acc+b1) -> x2t LDS [130][520] bf16 (rows 128/129 = 0).
//   phase B: KW=3 conv via MFMA (W2 from L2, x2 from LDS) -> x3b.
//   phase C: h1 copy + sigmoid/affine/out + logdet reduce.
// lb = t*126 - 1; x2 col ll <-> l_glob = lb+ll; valid outputs l_loc in [0,126).
// ---------------------------------------------------------------------------
__global__ void __launch_bounds__(512, 2) k_fused4(
    const float* __restrict__ h,
    const unsigned short* __restrict__ W1bf, const float* __restrict__ b1,
    const unsigned short* __restrict__ W2bf, const float* __restrict__ b2,
    const float* __restrict__ dynW, const float* __restrict__ dynB,
    float* __restrict__ out)
{
  extern __shared__ char smem[];
  unsigned short* x2t = (unsigned short*)smem;            // [130][520] bf16
  float* x3b = (float*)(smem + 135200);                   // [128][36]
  float* red = (float*)(smem + 153632);                   // [8]

  int tid = threadIdx.x;
  int t = blockIdx.x, s = blockIdx.y;
  int lb = t*126 - 1;
  int w = tid >> 6, ln16 = tid & 15, quad = (tid & 63) >> 4;
  int ot = w & 3, lh = w >> 2;
  int o_base = ot*128, l_base = lh*64;

  const float* hb = h + s*(NSQ*Lc);
  const float* dwp = dynW + s*1536;
  const float* dbp = dynB + s*Cc;

  floatx4 acc[8][4];
  #pragma unroll
  for (int mi = 0; mi < 8; mi++)
    #pragma unroll
    for (int ni = 0; ni < 4; ni++)
      acc[mi][ni] = (floatx4){0.f,0.f,0.f,0.f};

  // -------- phase A: 16 K-chunks, barrier-free --------
  for (int ch = 0; ch < 16; ch++) {
    int c0 = ch*32;
    int cb = c0 + quad*8;          // this lane's 8-channel group
    // A-frags from L2 (8 x 16B per lane)
    bf16x8 af[8];
    #pragma unroll
    for (int mi = 0; mi < 8; mi++)
      af[mi] = *(const bf16x8*)&W1bf[(o_base + mi*16 + ln16)*512 + cb];
    // dynamic weights for 8 channels (quad-uniform -> L1 broadcast)
    float wv[24], bx[8];
    {
      const float4* wp = (const float4*)(dwp + cb*3);
      #pragma unroll
      for (int i = 0; i < 6; i++) {
        float4 v = wp[i];
        wv[4*i] = v.x; wv[4*i+1] = v.y; wv[4*i+2] = v.z; wv[4*i+3] = v.w;
      }
      float4 b0 = *(const float4*)(dbp + cb);
      float4 b1v = *(const float4*)(dbp + cb + 4);
      bx[0]=b0.x; bx[1]=b0.y; bx[2]=b0.z; bx[3]=b0.w;
      bx[4]=b1v.x; bx[5]=b1v.y; bx[6]=b1v.z; bx[7]=b1v.w;
    }
    // h window for the 4 l-frags (row q == ch)
    const float* hr = hb + ch*Lc;
    float hv[12];
    #pragma unroll
    for (int ni = 0; ni < 4; ni++) {
      int gl = lb + l_base + ni*16 + ln16;
      #pragma unroll
      for (int m = 0; m < 3; m++) {
        int ii = gl - 1 + m;
        hv[ni*3+m] = ((unsigned)ii < 2048u) ? hr[ii] : 0.f;
      }
    }
    // compute B-frags in-register and MFMA
    #pragma unroll
    for (int ni = 0; ni < 4; ni++) {
      float hm = hv[ni*3], hc = hv[ni*3+1], hp = hv[ni*3+2];
      bf16x8 bfr;
      #pragma unroll
      for (int j = 0; j < 8; j++) {
        float v = fmaxf(wv[3*j]*hm + wv[3*j+1]*hc + wv[3*j+2]*hp + bx[j], 0.f);
        bfr[j] = (__bf16)v;
      }
      #pragma unroll
      for (int mi = 0; mi < 8; mi++)
        acc[mi][ni] = __builtin_amdgcn_mfma_f32_16x16x32_bf16(af[mi], bfr, acc[mi][ni], 0, 0, 0);
    }
  }

  // -------- epilogue A: relu+b1 -> x2t (bf16), zero-pad invalid l --------
  #pragma unroll
  for (int mi = 0; mi < 8; mi++) {
    int o = o_base + mi*16 + quad*4;
    float4 b1v = *(const float4*)(b1 + o);
    #pragma unroll
    for (int ni = 0; ni < 4; ni++) {
      int ll = l_base + ni*16 + ln16;
      int gl = lb + ll;
      ushort4 st;
      if ((unsigned)gl < 2048u) {
        st.x = f2bf(fmaxf(acc[mi][ni][0] + b1v.x, 0.f));
        st.y = f2bf(fmaxf(acc[mi][ni][1] + b1v.y, 0.f));
        st.z = f2bf(fmaxf(acc[mi][ni][2] + b1v.z, 0.f));
        st.w = f2bf(fmaxf(acc[mi][ni][3] + b1v.w, 0.f));
      } else {
        st.x = 0; st.y = 0; st.z = 0; st.w = 0;   // conv2 zero-pad columns
      }
      *(ushort4*)&x2t[ll*520 + o] = st;
    }
  }
  for (int i = tid; i < 520; i += 512)
    ((uint32_t*)&x2t[128*520])[i] = 0u;            // rows 128,129 = 0
  __syncthreads();

  // -------- phase B: KW=3 conv via MFMA; wave = (jh, nt 0..3) --------
  {
    int jh = w & 1, nt = w >> 1;
    floatx4 ca[2];
    ca[0] = (floatx4){0.f,0.f,0.f,0.f};
    ca[1] = (floatx4){0.f,0.f,0.f,0.f};
    #pragma unroll
    for (int k = 0; k < 3; k++) {
      const unsigned short* Wk = W2bf + k*16384 + (jh*16 + ln16)*512;
      #pragma unroll
      for (int c0 = 0; c0 < 512; c0 += 32) {
        bf16x8 a0 = *(const bf16x8*)&Wk[c0 + quad*8];
        #pragma unroll
        for (int ni = 0; ni < 2; ni++) {
          int lrow = nt*32 + ni*16 + ln16 + k;
          bf16x8 v0 = *(const bf16x8*)&x2t[lrow*520 + c0 + quad*8];
          ca[ni] = __builtin_amdgcn_mfma_f32_16x16x32_bf16(a0, v0, ca[ni], 0, 0, 0);
        }
      }
    }
    float4 b2v = *(const float4*)(b2 + jh*16 + quad*4);
    #pragma unroll
    for (int ni = 0; ni < 2; ni++) {
      int l_loc = nt*32 + ni*16 + ln16;
      float4 st;
      st.x = ca[ni][0] + b2v.x;
      st.y = ca[ni][1] + b2v.y;
      st.z = ca[ni][2] + b2v.z;
      st.w = ca[ni][3] + b2v.w;
      *(float4*)&x3b[l_loc*36 + jh*16 + quad*4] = st;
    }
  }
  __syncthreads();

  // -------- phase C: h1 copy + sigmoid/affine/out + logdet --------
  float ld = 0.f;
  #pragma unroll
  for (int i = 0; i < 8; i++) {
    int idx = tid + i*512;           // 0..4095 = (q 0..31) x (l_loc 0..127)
    int l_loc = idx & 127, q = idx >> 7;
    int l = t*126 + l_loc;
    if (l_loc < 126 && l < 2048) {
      int gi = s*(NSQ*Lc) + q*Lc + l;
      if (q < 16) {
        out[gi] = h[gi];             // h1 passthrough
      } else {
        float sv = 1.f / (1.f + __expf(-(x3b[l_loc*36 + (q-16)] + 2.f))) + 1e-7f;
        float mv = x3b[l_loc*36 + (q-16) + 16];
        out[gi] = sv * (h[gi] + mv);
        ld += __logf(sv);
      }
    }
  }
  #pragma unroll
  for (int off = 32; off > 0; off >>= 1) ld += __shfl_down(ld, off);
  if ((tid & 63) == 0) red[w] = ld;
  __syncthreads();
  if (tid == 0) {
    float tot = 0.f;
    #pragma unroll
    for (int i = 0; i < 8; i++) tot += red[i];
    atomicAdd(&out[OUT_H + s], tot);
  }
}

// ---------------------------------------------------------------------------
extern "C" void kernel_launch(void* const* d_in, const int* in_sizes, int n_in,
                              void* d_out, int out_size, void* d_ws, size_t ws_size,
                              hipStream_t stream) {
  const float* h   = (const float*)d_in[0];
  const float* emb = (const float*)d_in[1];
  const float* Wa  = (const float*)d_in[2];
  const float* ba  = (const float*)d_in[3];
  const float* Wb  = (const float*)d_in[4];
  const float* bb  = (const float*)d_in[5];
  const float* W1  = (const float*)d_in[6];
  const float* b1  = (const float*)d_in[7];
  const float* W2  = (const float*)d_in[8];
  const float* b2  = (const float*)d_in[9];
  float* out = (float*)d_out;
  char* ws = (char*)d_ws;

  float* dynW = (float*)(ws + 0);                          // 384 KiB
  float* dynB = (float*)(ws + 393216);                     // 128 KiB
  unsigned short* W1bf = (unsigned short*)(ws + 524288);   // 512 KiB
  unsigned short* W2bf = (unsigned short*)(ws + 1048576);  // 96 KiB
  if (ws_size < 1179648ull) return;                        // ~1.2 MB needed

  const int smem_bytes = 153664;  // x2t 135200 + x3b 18432 + red 32
  (void)hipFuncSetAttribute((const void*)k_fused4,
                            hipFuncAttributeMaxDynamicSharedMemorySize,
                            smem_bytes);

  k_prep<<<512, 256, 0, stream>>>(emb, Wa, ba, Wb, bb, W1, W2,
                                  dynW, dynB, W1bf, W2bf, out);
  k_fused4<<<dim3(17, 64), 512, smem_bytes, stream>>>(h, W1bf, b1, W2bf, b2,
                                                      dynW, dynB, out);
}

// Round 8
// 336.684 us; speedup vs baseline: 2.0313x; 1.2406x over previous
//
#include <hip/hip_runtime.h>
#include <stdint.h>

#define S 64
#define NSQ 32
#define Lc 2048
#define Cc 512
#define Ec 128
#define OUT_H (S*NSQ*Lc)   /* 4194304 */

typedef __bf16 bf16x8 __attribute__((ext_vector_type(8)));
typedef float floatx4 __attribute__((ext_vector_type(4)));

__device__ __forceinline__ unsigned short f2bf(float f){
  union { float f; uint32_t u; } v; v.f = f;
  uint32_t r = v.u + 0x7fffu + ((v.u >> 16) & 1u);
  return (unsigned short)(r >> 16);
}

// ---------------------------------------------------------------------------
// k_prep: dynamic weights; W1 -> MFMA-fragment-packed bf16 W1p; W2 -> packed
// W2p; zero logdet.   grid 512 x 256
// W1p layout: frag_id = ch*32 + o16 (ch: 32-chan chunk, o16: 16-o tile);
//   W1p[frag_id*512 + lane*8 + j] = bf16(W1[o16*16 + (lane&15)]
//                                        [ch*32 + (lane>>4)*8 + j])
// W2p layout: frag_id = (k*2 + jh)*16 + cc;
//   W2p[frag_id*512 + lane*8 + j] = bf16(W2[jh*16+(lane&15)]
//                                        [cc*32+(lane>>4)*8+j][k])
// ---------------------------------------------------------------------------
__global__ void k_prep(const float* __restrict__ emb,
                       const float* __restrict__ Wa, const float* __restrict__ ba,
                       const float* __restrict__ Wb, const float* __restrict__ bb,
                       const float* __restrict__ W1, const float* __restrict__ W2,
                       float* __restrict__ dynW, float* __restrict__ dynB,
                       unsigned short* __restrict__ W1p, unsigned short* __restrict__ W2p,
                       float* __restrict__ out)
{
  __shared__ float embl[Ec];
  int tid = threadIdx.x;
  int b = blockIdx.x;          // 512 blocks, 8 per sample
  int s = b >> 3;
  int o = ((b & 7) << 8) | tid;   // 0..2047 (1536 dynW dots + 512 dynB dots)
  if (tid < Ec) embl[tid] = emb[s*Ec + tid];
  __syncthreads();
  const float* row; float bias; float* dst;
  if (o < 1536) { row = Wa + o*Ec; bias = ba[o]; dst = dynW + s*1536 + o; }
  else { int c = o - 1536; row = Wb + c*Ec; bias = bb[c]; dst = dynB + s*Cc + c; }
  float acc = bias;
  const float4* r4 = (const float4*)row;
  #pragma unroll 8
  for (int e = 0; e < Ec/4; e++) {
    float4 rv = r4[e];
    acc += embl[4*e]*rv.x + embl[4*e+1]*rv.y + embl[4*e+2]*rv.z + embl[4*e+3]*rv.w;
  }
  *dst = acc;

  int gtid = b*256 + tid;      // 0..131071
  // W1 pack: 262144 elems, 2 per thread (j pairs)
  {
    int d0 = gtid*2;
    int j0 = d0 & 7;
    int lane = (d0 >> 3) & 63;
    int frag = d0 >> 9;
    int o16 = frag & 31, ch = frag >> 5;
    int oo = o16*16 + (lane & 15);
    int cc = ch*32 + (lane >> 4)*8 + j0;
    float2 wv = *(const float2*)&W1[oo*512 + cc];
    uint32_t packed = (uint32_t)f2bf(wv.x) | ((uint32_t)f2bf(wv.y) << 16);
    ((uint32_t*)W1p)[gtid] = packed;
  }
  // W2 pack: 49152 elems
  if (gtid < 49152) {
    int d = gtid;
    int j = d & 7;
    int lane = (d >> 3) & 63;
    int frag = d >> 9;
    int k = frag >> 5, jh = (frag >> 4) & 1, cc = frag & 15;
    int jj = jh*16 + (lane & 15);
    int c = cc*32 + (lane >> 4)*8 + j;
    W2p[d] = f2bf(W2[jj*1536 + c*3 + k]);
  }
  if (gtid < S) out[OUT_H + gtid] = 0.f;   // logdet accumulators
}

// ---------------------------------------------------------------------------
// k_fused5: 8-wave (512-thr) block per (l-tile, sample); 1 block/CU.
//   stage:   h rows 0..15 window (132 cols) + dynW/dynB -> LDS; 1 barrier.
//   phase A (barrier-free): acc[512 o][128 ll] = W1 @ x; 16 K-chunks of 32c.
//     A-frags: packed W1p, coalesced 1KB/wave, double-buffered prefetch.
//     B-frags: computed per-lane (3-tap depthwise + relu) from LDS h/dyn.
//   epilogue A: relu(acc+b1) -> x2t LDS [130][532] bf16 (rows 128/129 = 0).
//   phase B: KW=3 conv via MFMA (packed W2p from L2, x2 from LDS) -> x3b.
//   phase C: h1 copy + sigmoid/affine/out + logdet reduce.
// lb = t*126 - 1; x2 col ll <-> l_glob = lb+ll; valid outputs l_loc in [0,126).
// ---------------------------------------------------------------------------
__global__ void __launch_bounds__(512, 2) k_fused5(
    const float* __restrict__ h,
    const unsigned short* __restrict__ W1p, const float* __restrict__ b1,
    const unsigned short* __restrict__ W2p, const float* __restrict__ b2,
    const float* __restrict__ dynW, const float* __restrict__ dynB,
    float* __restrict__ out)
{
  extern __shared__ char smem[];
  // staging region [0, 18432) is later reused as x3b
  float* hs  = (float*)smem;                              // [16][132]
  float* dws = (float*)(smem + 8448);                     // [1536]
  float* dbs = (float*)(smem + 14592);                    // [512]
  float* x3b = (float*)smem;                              // [128][36] (aliases)
  unsigned short* x2t = (unsigned short*)(smem + 18432);  // [130][532] bf16
  float* red = (float*)(smem + 156752);                   // [8]

  int tid = threadIdx.x;
  int t = blockIdx.x, s = blockIdx.y;
  int lb = t*126 - 1;
  int w = tid >> 6, ln16 = tid & 15, quad = (tid & 63) >> 4;
  int lane8 = (tid & 63)*8;
  int ot = w & 3, lh = w >> 2;
  int o_base = ot*128, l_base = lh*64;

  const float* hb = h + s*(NSQ*Lc);

  // -------- stage h window + dyn weights into LDS --------
  for (int i = tid; i < 16*132; i += 512) {
    int r = i / 132, col = i - r*132;
    int gl = t*126 - 2 + col;
    hs[i] = ((unsigned)gl < 2048u) ? hb[r*Lc + gl] : 0.f;
  }
  for (int i = tid; i < 1536; i += 512) dws[i] = dynW[s*1536 + i];
  if (tid < 512) dbs[tid] = dynB[s*Cc + tid];
  __syncthreads();

  floatx4 acc[8][4];
  #pragma unroll
  for (int mi = 0; mi < 8; mi++)
    #pragma unroll
    for (int ni = 0; ni < 4; ni++)
      acc[mi][ni] = (floatx4){0.f,0.f,0.f,0.f};

  #define LOADAF(ch_, AF_) {                                                  \
    _Pragma("unroll")                                                         \
    for (int mi = 0; mi < 8; mi++)                                            \
      (AF_)[mi] = *(const bf16x8*)&W1p[(((ch_)*32 + ot*8 + mi) << 9) + lane8];\
  }

  #define CHUNK(ch_, AFC_, AFN_, PF_) {                                       \
    if (PF_) LOADAF((ch_) + 1, AFN_);                                         \
    int cb_ = (ch_)*32 + quad*8;                                              \
    float wvv[24], bxx[8];                                                    \
    {                                                                         \
      const float4* wp4 = (const float4*)&dws[cb_*3];                         \
      _Pragma("unroll")                                                       \
      for (int i = 0; i < 6; i++) {                                           \
        float4 v = wp4[i];                                                    \
        wvv[4*i] = v.x; wvv[4*i+1] = v.y; wvv[4*i+2] = v.z; wvv[4*i+3] = v.w; \
      }                                                                       \
      float4 b0_ = *(const float4*)&dbs[cb_];                                 \
      float4 b1_ = *(const float4*)&dbs[cb_ + 4];                             \
      bxx[0]=b0_.x; bxx[1]=b0_.y; bxx[2]=b0_.z; bxx[3]=b0_.w;                 \
      bxx[4]=b1_.x; bxx[5]=b1_.y; bxx[6]=b1_.z; bxx[7]=b1_.w;                 \
    }                                                                         \
    const float* hrow_ = hs + (ch_)*132;                                      \
    _Pragma("unroll")                                                         \
    for (int ni = 0; ni < 4; ni++) {                                          \
      int col_ = l_base + ni*16 + ln16;                                       \
      float hm = hrow_[col_], hc = hrow_[col_+1], hp = hrow_[col_+2];         \
      bf16x8 bfr;                                                             \
      _Pragma("unroll")                                                       \
      for (int j = 0; j < 8; j++) {                                           \
        float v = fmaxf(wvv[3*j]*hm + wvv[3*j+1]*hc + wvv[3*j+2]*hp + bxx[j], 0.f); \
        bfr[j] = (__bf16)v;                                                   \
      }                                                                       \
      _Pragma("unroll")                                                       \
      for (int mi = 0; mi < 8; mi++)                                          \
        acc[mi][ni] = __builtin_amdgcn_mfma_f32_16x16x32_bf16((AFC_)[mi], bfr, acc[mi][ni], 0, 0, 0); \
    }                                                                         \
  }

  // -------- phase A: 16 K-chunks, barrier-free, af double-buffered --------
  {
    bf16x8 afA[8], afB[8];
    LOADAF(0, afA);
    #pragma unroll 1
    for (int cp = 0; cp < 8; cp++) {
      CHUNK(2*cp,     afA, afB, 1);
      CHUNK(2*cp + 1, afB, afA, (cp < 7));
    }
  }

  // -------- epilogue A: relu+b1 -> x2t (bf16), zero-pad invalid l --------
  #pragma unroll
  for (int mi = 0; mi < 8; mi++) {
    int o = o_base + mi*16 + quad*4;
    float4 b1v = *(const float4*)(b1 + o);
    #pragma unroll
    for (int ni = 0; ni < 4; ni++) {
      int ll = l_base + ni*16 + ln16;
      int gl = lb + ll;
      ushort4 st;
      if ((unsigned)gl < 2048u) {
        st.x = f2bf(fmaxf(acc[mi][ni][0] + b1v.x, 0.f));
        st.y = f2bf(fmaxf(acc[mi][ni][1] + b1v.y, 0.f));
        st.z = f2bf(fmaxf(acc[mi][ni][2] + b1v.z, 0.f));
        st.w = f2bf(fmaxf(acc[mi][ni][3] + b1v.w, 0.f));
      } else {
        st.x = 0; st.y = 0; st.z = 0; st.w = 0;   // conv2 zero-pad columns
      }
      *(ushort4*)&x2t[ll*532 + o] = st;
    }
  }
  for (int i = tid; i < 532; i += 512)
    ((uint32_t*)&x2t[128*532])[i] = 0u;            // rows 128,129 = 0
  __syncthreads();

  // -------- phase B: KW=3 conv via MFMA; wave = (jh, nt 0..3) --------
  {
    int jh = w & 1, nt = w >> 1;
    floatx4 ca[2];
    ca[0] = (floatx4){0.f,0.f,0.f,0.f};
    ca[1] = (floatx4){0.f,0.f,0.f,0.f};
    #pragma unroll
    for (int k = 0; k < 3; k++) {
      #pragma unroll
      for (int cc = 0; cc < 16; cc++) {
        bf16x8 a0 = *(const bf16x8*)&W2p[((((k*2 + jh)*16) + cc) << 9) + lane8];
        #pragma unroll
        for (int ni = 0; ni < 2; ni++) {
          int lrow = nt*32 + ni*16 + ln16 + k;
          bf16x8 v0 = *(const bf16x8*)&x2t[lrow*532 + cc*32 + quad*8];
          ca[ni] = __builtin_amdgcn_mfma_f32_16x16x32_bf16(a0, v0, ca[ni], 0, 0, 0);
        }
      }
    }
    float4 b2v = *(const float4*)(b2 + jh*16 + quad*4);
    #pragma unroll
    for (int ni = 0; ni < 2; ni++) {
      int l_loc = nt*32 + ni*16 + ln16;
      float4 st;
      st.x = ca[ni][0] + b2v.x;
      st.y = ca[ni][1] + b2v.y;
      st.z = ca[ni][2] + b2v.z;
      st.w = ca[ni][3] + b2v.w;
      *(float4*)&x3b[l_loc*36 + jh*16 + quad*4] = st;
    }
  }
  __syncthreads();

  // -------- phase C: h1 copy + sigmoid/affine/out + logdet --------
  float ld = 0.f;
  #pragma unroll
  for (int i = 0; i < 8; i++) {
    int idx = tid + i*512;           // 0..4095 = (q 0..31) x (l_loc 0..127)
    int l_loc = idx & 127, q = idx >> 7;
    int l = t*126 + l_loc;
    if (l_loc < 126 && l < 2048) {
      int gi = s*(NSQ*Lc) + q*Lc + l;
      if (q < 16) {
        out[gi] = h[gi];             // h1 passthrough
      } else {
        float sv = 1.f / (1.f + __expf(-(x3b[l_loc*36 + (q-16)] + 2.f))) + 1e-7f;
        float mv = x3b[l_loc*36 + (q-16) + 16];
        out[gi] = sv * (h[gi] + mv);
        ld += __logf(sv);
      }
    }
  }
  #pragma unroll
  for (int off = 32; off > 0; off >>= 1) ld += __shfl_down(ld, off);
  if ((tid & 63) == 0) red[w] = ld;
  __syncthreads();
  if (tid == 0) {
    float tot = 0.f;
    #pragma unroll
    for (int i = 0; i < 8; i++) tot += red[i];
    atomicAdd(&out[OUT_H + s], tot);
  }
}

// ---------------------------------------------------------------------------
extern "C" void kernel_launch(void* const* d_in, const int* in_sizes, int n_in,
                              void* d_out, int out_size, void* d_ws, size_t ws_size,
                              hipStream_t stream) {
  const float* h   = (const float*)d_in[0];
  const float* emb = (const float*)d_in[1];
  const float* Wa  = (const float*)d_in[2];
  const float* ba  = (const float*)d_in[3];
  const float* Wb  = (const float*)d_in[4];
  const float* bb  = (const float*)d_in[5];
  const float* W1  = (const float*)d_in[6];
  const float* b1  = (const float*)d_in[7];
  const float* W2  = (const float*)d_in[8];
  const float* b2  = (const float*)d_in[9];
  float* out = (float*)d_out;
  char* ws = (char*)d_ws;

  float* dynW = (float*)(ws + 0);                          // 384 KiB
  float* dynB = (float*)(ws + 393216);                     // 128 KiB
  unsigned short* W1p = (unsigned short*)(ws + 524288);    // 512 KiB (packed)
  unsigned short* W2p = (unsigned short*)(ws + 1048576);   // 96 KiB (packed)
  if (ws_size < 1179648ull) return;                        // ~1.2 MB needed

  const int smem_bytes = 156800;  // stage/x3b 18432 + x2t 138320 + red 32 (+pad)
  (void)hipFuncSetAttribute((const void*)k_fused5,
                            hipFuncAttributeMaxDynamicSharedMemorySize,
                            smem_bytes);

  k_prep<<<512, 256, 0, stream>>>(emb, Wa, ba, Wb, bb, W1, W2,
                                  dynW, dynB, W1p, W2p, out);
  k_fused5<<<dim3(17, 64), 512, smem_bytes, stream>>>(h, W1p, b1, W2p, b2,
                                                      dynW, dynB, out);
}

// Round 9
// 209.547 us; speedup vs baseline: 3.2637x; 1.6067x over previous
//
#include <hip/hip_runtime.h>
#include <stdint.h>

#define S 64
#define NSQ 32
#define Lc 2048
#define Cc 512
#define Ec 128
#define OUT_H (S*NSQ*Lc)   /* 4194304 */

typedef __bf16 bf16x8 __attribute__((ext_vector_type(8)));
typedef float floatx4 __attribute__((ext_vector_type(4)));

__device__ __forceinline__ unsigned short f2bf(float f){
  union { float f; uint32_t u; } v; v.f = f;
  uint32_t r = v.u + 0x7fffu + ((v.u >> 16) & 1u);
  return (unsigned short)(r >> 16);
}

// ---------------------------------------------------------------------------
// k_prep: dynamic weights; W1/W2 -> MFMA-fragment-packed bf16; zero logdet.
// W1p: frag_id = ch*32 + o16; W1p[frag*512 + lane*8 + j] =
//        bf16(W1[o16*16 + (lane&15)][ch*32 + (lane>>4)*8 + j])
// W2p: frag_id = (k*2 + jh)*16 + cc; element (lane,j) =
//        bf16(W2[jh*16+(lane&15)][cc*32+(lane>>4)*8+j][k])
// ---------------------------------------------------------------------------
__global__ void k_prep(const float* __restrict__ emb,
                       const float* __restrict__ Wa, const float* __restrict__ ba,
                       const float* __restrict__ Wb, const float* __restrict__ bb,
                       const float* __restrict__ W1, const float* __restrict__ W2,
                       float* __restrict__ dynW, float* __restrict__ dynB,
                       unsigned short* __restrict__ W1p, unsigned short* __restrict__ W2p,
                       float* __restrict__ out)
{
  __shared__ float embl[Ec];
  int tid = threadIdx.x;
  int b = blockIdx.x;          // 512 blocks, 8 per sample
  int s = b >> 3;
  int o = ((b & 7) << 8) | tid;   // 0..2047 (1536 dynW dots + 512 dynB dots)
  if (tid < Ec) embl[tid] = emb[s*Ec + tid];
  __syncthreads();
  const float* row; float bias; float* dst;
  if (o < 1536) { row = Wa + o*Ec; bias = ba[o]; dst = dynW + s*1536 + o; }
  else { int c = o - 1536; row = Wb + c*Ec; bias = bb[c]; dst = dynB + s*Cc + c; }
  float acc = bias;
  const float4* r4 = (const float4*)row;
  #pragma unroll 8
  for (int e = 0; e < Ec/4; e++) {
    float4 rv = r4[e];
    acc += embl[4*e]*rv.x + embl[4*e+1]*rv.y + embl[4*e+2]*rv.z + embl[4*e+3]*rv.w;
  }
  *dst = acc;

  int gtid = b*256 + tid;      // 0..131071
  // W1 pack: 262144 elems, 2 per thread (j pairs)
  {
    int d0 = gtid*2;
    int j0 = d0 & 7;
    int lane = (d0 >> 3) & 63;
    int frag = d0 >> 9;
    int o16 = frag & 31, ch = frag >> 5;
    int oo = o16*16 + (lane & 15);
    int cc = ch*32 + (lane >> 4)*8 + j0;
    float2 wv = *(const float2*)&W1[oo*512 + cc];
    uint32_t packed = (uint32_t)f2bf(wv.x) | ((uint32_t)f2bf(wv.y) << 16);
    ((uint32_t*)W1p)[gtid] = packed;
  }
  // W2 pack: 49152 elems
  if (gtid < 49152) {
    int d = gtid;
    int j = d & 7;
    int lane = (d >> 3) & 63;
    int frag = d >> 9;
    int k = frag >> 5, jh = (frag >> 4) & 1, cc = frag & 15;
    int jj = jh*16 + (lane & 15);
    int c = cc*32 + (lane >> 4)*8 + j;
    W2p[d] = f2bf(W2[jj*1536 + c*3 + k]);
  }
  if (gtid < S) out[OUT_H + gtid] = 0.f;   // logdet accumulators
}

// ---------------------------------------------------------------------------
// k_fused6: 4-wave (256-thr) block per (l-tile, sample); 2 blocks/CU.
//   stage:  h rows (16x68) + dynW/dynB -> LDS; compute x[64 ll][512 c] bf16
//           into LDS ONCE (no redundancy); 2 barriers.
//   phase A (barrier-free): acc[512 o][64 ll] = W1p @ x; 16 K-chunks;
//           wave = o-tile of 128; af double-buffered from L2 (packed);
//           B-frags via ds_read_b128 from x.
//   epilogue A: relu(acc+b1) -> x2t (reuses x region; zero for invalid l).
//   phase B: KW=3 conv via MFMA (W2p from L2, x2t from LDS) -> x3b.
//   phase C: h1 copy + sigmoid/affine/out + logdet reduce.
// lb = t*62 - 1; col ll 0..63 <-> global l = lb+ll; valid outputs ll in [1,62].
// ---------------------------------------------------------------------------
__global__ void __launch_bounds__(256, 2) k_fused6(
    const float* __restrict__ h,
    const unsigned short* __restrict__ W1p, const float* __restrict__ b1,
    const unsigned short* __restrict__ W2p, const float* __restrict__ b2,
    const float* __restrict__ dynW, const float* __restrict__ dynB,
    float* __restrict__ out)
{
  extern __shared__ char smem[];
  float* hs  = (float*)smem;                              // [16][68]
  float* dws = (float*)(smem + 4352);                     // [1536]
  float* dbs = (float*)(smem + 10496);                    // [512]
  float* x3b = (float*)smem;                              // [64][36] (aliases stage)
  unsigned short* xt = (unsigned short*)(smem + 12544);   // [64][528] x then x2
  float* red = (float*)(smem + 80128);                    // [4]

  int tid = threadIdx.x;
  int t = blockIdx.x, s = blockIdx.y;
  int lb = t*62 - 1;
  int w = tid >> 6, ln16 = tid & 15, quad = (tid & 63) >> 4;
  int lane8 = (tid & 63)*8;

  const float* hb = h + s*(NSQ*Lc);

  // -------- stage h window + dyn weights --------
  for (int i = tid; i < 16*68; i += 256) {
    int r = i >> 6;  // careful: 68 stride -> use div
    r = i / 68; int col = i - r*68;
    int gl = lb - 1 + col;
    hs[i] = ((unsigned)gl < 2048u) ? hb[r*Lc + gl] : 0.f;
  }
  for (int i = tid; i < 1536; i += 256) dws[i] = dynW[s*1536 + i];
  for (int i = tid; i < 512; i += 256) dbs[i] = dynB[s*Cc + i];
  __syncthreads();

  // -------- compute x once: thread = (cg 0..63, lg=w 0..3) --------
  {
    int cg = tid & 63;
    int c8 = cg*8, q = cg >> 2;
    float wvv[24], bxx[8];
    const float4* wp4 = (const float4*)&dws[c8*3];
    #pragma unroll
    for (int i = 0; i < 6; i++) {
      float4 v = wp4[i];
      wvv[4*i] = v.x; wvv[4*i+1] = v.y; wvv[4*i+2] = v.z; wvv[4*i+3] = v.w;
    }
    float4 b0 = *(const float4*)&dbs[c8];
    float4 b1v = *(const float4*)&dbs[c8 + 4];
    bxx[0]=b0.x; bxx[1]=b0.y; bxx[2]=b0.z; bxx[3]=b0.w;
    bxx[4]=b1v.x; bxx[5]=b1v.y; bxx[6]=b1v.z; bxx[7]=b1v.w;
    const float* hr = hs + q*68;
    #pragma unroll
    for (int i = 0; i < 16; i++) {
      int ll = w*16 + i;
      float hm = hr[ll], hc = hr[ll+1], hp = hr[ll+2];
      ushort4 s0, s1;
      float v0 = fmaxf(wvv[0]*hm + wvv[1]*hc + wvv[2]*hp + bxx[0], 0.f);
      float v1 = fmaxf(wvv[3]*hm + wvv[4]*hc + wvv[5]*hp + bxx[1], 0.f);
      float v2 = fmaxf(wvv[6]*hm + wvv[7]*hc + wvv[8]*hp + bxx[2], 0.f);
      float v3 = fmaxf(wvv[9]*hm + wvv[10]*hc + wvv[11]*hp + bxx[3], 0.f);
      float v4 = fmaxf(wvv[12]*hm + wvv[13]*hc + wvv[14]*hp + bxx[4], 0.f);
      float v5 = fmaxf(wvv[15]*hm + wvv[16]*hc + wvv[17]*hp + bxx[5], 0.f);
      float v6 = fmaxf(wvv[18]*hm + wvv[19]*hc + wvv[20]*hp + bxx[6], 0.f);
      float v7 = fmaxf(wvv[21]*hm + wvv[22]*hc + wvv[23]*hp + bxx[7], 0.f);
      s0.x = f2bf(v0); s0.y = f2bf(v1); s0.z = f2bf(v2); s0.w = f2bf(v3);
      s1.x = f2bf(v4); s1.y = f2bf(v5); s1.z = f2bf(v6); s1.w = f2bf(v7);
      *(ushort4*)&xt[ll*528 + c8] = s0;
      *(ushort4*)&xt[ll*528 + c8 + 4] = s1;
    }
  }
  __syncthreads();

  floatx4 acc[8][4];
  #pragma unroll
  for (int mi = 0; mi < 8; mi++)
    #pragma unroll
    for (int ni = 0; ni < 4; ni++)
      acc[mi][ni] = (floatx4){0.f,0.f,0.f,0.f};

  #define LOADAF(ch_, AF_) {                                                  \
    _Pragma("unroll")                                                         \
    for (int mi = 0; mi < 8; mi++)                                            \
      (AF_)[mi] = *(const bf16x8*)&W1p[(((ch_)*32 + w*8 + mi) << 9) + lane8]; \
  }

  #define CHUNK(ch_, AFC_, AFN_, PF_) {                                       \
    if (PF_) LOADAF((ch_) + 1, AFN_);                                         \
    _Pragma("unroll")                                                         \
    for (int ni = 0; ni < 4; ni++) {                                          \
      bf16x8 bfr = *(const bf16x8*)&xt[(ni*16 + ln16)*528 + (ch_)*32 + quad*8]; \
      _Pragma("unroll")                                                       \
      for (int mi = 0; mi < 8; mi++)                                          \
        acc[mi][ni] = __builtin_amdgcn_mfma_f32_16x16x32_bf16((AFC_)[mi], bfr, acc[mi][ni], 0, 0, 0); \
    }                                                                         \
  }

  // -------- phase A: 16 K-chunks, barrier-free, af double-buffered --------
  {
    bf16x8 afA[8], afB[8];
    LOADAF(0, afA);
    #pragma unroll 1
    for (int cp = 0; cp < 8; cp++) {
      CHUNK(2*cp,     afA, afB, 1);
      CHUNK(2*cp + 1, afB, afA, (cp < 7));
    }
  }
  __syncthreads();   // all x reads done before x2 overwrites the region

  // -------- epilogue A: relu+b1 -> x2 in xt (bf16), zero invalid l --------
  #pragma unroll
  for (int mi = 0; mi < 8; mi++) {
    int o = w*128 + mi*16 + quad*4;
    float4 b1v = *(const float4*)(b1 + o);
    #pragma unroll
    for (int ni = 0; ni < 4; ni++) {
      int ll = ni*16 + ln16;
      int gl = lb + ll;
      ushort4 st;
      if ((unsigned)gl < 2048u) {
        st.x = f2bf(fmaxf(acc[mi][ni][0] + b1v.x, 0.f));
        st.y = f2bf(fmaxf(acc[mi][ni][1] + b1v.y, 0.f));
        st.z = f2bf(fmaxf(acc[mi][ni][2] + b1v.z, 0.f));
        st.w = f2bf(fmaxf(acc[mi][ni][3] + b1v.w, 0.f));
      } else {
        st.x = 0; st.y = 0; st.z = 0; st.w = 0;   // conv2 zero-pad columns
      }
      *(ushort4*)&xt[ll*528 + o] = st;
    }
  }
  __syncthreads();

  // -------- phase B: KW=3 conv via MFMA; wave = (jh, nt 0..1) --------
  {
    int jh = w & 1, nt = w >> 1;
    floatx4 ca[2];
    ca[0] = (floatx4){0.f,0.f,0.f,0.f};
    ca[1] = (floatx4){0.f,0.f,0.f,0.f};
    #pragma unroll
    for (int k = 0; k < 3; k++) {
      #pragma unroll
      for (int ni = 0; ni < 2; ni++) {
        int ll = nt*32 + ni*16 + ln16;
        int rowc = ll - 1 + k;
        rowc = (rowc < 0) ? 0 : ((rowc > 63) ? 63 : rowc);  // edges discarded
        const unsigned short* xr = xt + rowc*528;
        #pragma unroll
        for (int cc = 0; cc < 16; cc += 2) {
          bf16x8 a0 = *(const bf16x8*)&W2p[(((k*2 + jh)*16 + cc) << 9) + lane8];
          bf16x8 v0 = *(const bf16x8*)&xr[cc*32 + quad*8];
          ca[ni] = __builtin_amdgcn_mfma_f32_16x16x32_bf16(a0, v0, ca[ni], 0, 0, 0);
          bf16x8 a1 = *(const bf16x8*)&W2p[(((k*2 + jh)*16 + cc + 1) << 9) + lane8];
          bf16x8 v1 = *(const bf16x8*)&xr[(cc + 1)*32 + quad*8];
          ca[ni] = __builtin_amdgcn_mfma_f32_16x16x32_bf16(a1, v1, ca[ni], 0, 0, 0);
        }
      }
    }
    float4 b2v = *(const float4*)(b2 + jh*16 + quad*4);
    #pragma unroll
    for (int ni = 0; ni < 2; ni++) {
      int ll = nt*32 + ni*16 + ln16;
      float4 st;
      st.x = ca[ni][0] + b2v.x;
      st.y = ca[ni][1] + b2v.y;
      st.z = ca[ni][2] + b2v.z;
      st.w = ca[ni][3] + b2v.w;
      *(float4*)&x3b[ll*36 + jh*16 + quad*4] = st;
    }
  }
  __syncthreads();

  // -------- phase C: h1 copy + sigmoid/affine/out + logdet --------
  float ld = 0.f;
  #pragma unroll
  for (int i = 0; i < 8; i++) {
    int idx = tid + i*256;           // 0..2047 = (q 0..31) x (ll 0..63)
    int ll = idx & 63, q = idx >> 6;
    int l = lb + ll;
    if (ll >= 1 && ll <= 62 && l < 2048) {
      int gi = s*(NSQ*Lc) + q*Lc + l;
      if (q < 16) {
        out[gi] = h[gi];             // h1 passthrough
      } else {
        float sv = 1.f / (1.f + __expf(-(x3b[ll*36 + (q-16)] + 2.f))) + 1e-7f;
        float mv = x3b[ll*36 + (q-16) + 16];
        out[gi] = sv * (h[gi] + mv);
        ld += __logf(sv);
      }
    }
  }
  #pragma unroll
  for (int off = 32; off > 0; off >>= 1) ld += __shfl_down(ld, off);
  if ((tid & 63) == 0) red[w] = ld;
  __syncthreads();
  if (tid == 0) {
    atomicAdd(&out[OUT_H + s], red[0] + red[1] + red[2] + red[3]);
  }
}

// ---------------------------------------------------------------------------
extern "C" void kernel_launch(void* const* d_in, const int* in_sizes, int n_in,
                              void* d_out, int out_size, void* d_ws, size_t ws_size,
                              hipStream_t stream) {
  const float* h   = (const float*)d_in[0];
  const float* emb = (const float*)d_in[1];
  const float* Wa  = (const float*)d_in[2];
  const float* ba  = (const float*)d_in[3];
  const float* Wb  = (const float*)d_in[4];
  const float* bb  = (const float*)d_in[5];
  const float* W1  = (const float*)d_in[6];
  const float* b1  = (const float*)d_in[7];
  const float* W2  = (const float*)d_in[8];
  const float* b2  = (const float*)d_in[9];
  float* out = (float*)d_out;
  char* ws = (char*)d_ws;

  float* dynW = (float*)(ws + 0);                          // 384 KiB
  float* dynB = (float*)(ws + 393216);                     // 128 KiB
  unsigned short* W1p = (unsigned short*)(ws + 524288);    // 512 KiB (packed)
  unsigned short* W2p = (unsigned short*)(ws + 1048576);   // 96 KiB (packed)
  if (ws_size < 1179648ull) return;                        // ~1.2 MB needed

  const int smem_bytes = 80144;  // stage 12544 + xt 67584 + red 16
  (void)hipFuncSetAttribute((const void*)k_fused6,
                            hipFuncAttributeMaxDynamicSharedMemorySize,
                            smem_bytes);

  k_prep<<<512, 256, 0, stream>>>(emb, Wa, ba, Wb, bb, W1, W2,
                                  dynW, dynB, W1p, W2p, out);
  k_fused6<<<dim3(34, 64), 256, smem_bytes, stream>>>(h, W1p, b1, W2p, b2,
                                                      dynW, dynB, out);
}